// Round 18
// baseline (574.834 us; speedup 1.0000x reference)
//
#include <hip/hip_runtime.h>
#include <hip/hip_bf16.h>
#include <float.h>
#include <math.h>

typedef __hip_bfloat16 bf16;
typedef float v2f __attribute__((ext_vector_type(2)));

#define NEGBIG (-1e30f)

__device__ __forceinline__ float ldv(const float* p, int i) { return p[i]; }

__device__ __forceinline__ float wave_sum(float v) {
#pragma unroll
  for (int off = 32; off; off >>= 1) v += __shfl_xor(v, off, 64);
  return v;
}
__device__ __forceinline__ float wave_max(float v) {
#pragma unroll
  for (int off = 32; off; off >>= 1) v = fmaxf(v, __shfl_xor(v, off, 64));
  return v;
}

// QK dot against one 32-token K block slice, packed (v_pk_fma_f32).
// d01 accumulates (x,y) products, d23 (z,w); final (d01+d23).x + (d01+d23).y.
__device__ __forceinline__ float qk_dot(const float4* __restrict__ qr,
                                        const float4* __restrict__ kp) {
  v2f d01 = {0.f, 0.f}, d23 = {0.f, 0.f};
#pragma unroll 1
  for (int i = 0; i < 16; i += 2) {
    float4 q0 = qr[i],     k0 = kp[i * 32];
    float4 q1 = qr[i + 1], k1 = kp[i * 32 + 32];
    d01 += (v2f){q0.x, q0.y} * (v2f){k0.x, k0.y};
    d23 += (v2f){q0.z, q0.w} * (v2f){k0.z, k0.w};
    d01 += (v2f){q1.x, q1.y} * (v2f){k1.x, k1.y};
    d23 += (v2f){q1.z, q1.w} * (v2f){k1.z, k1.w};
  }
  v2f d = d01 + d23;
  return d.x + d.y;
}

// ---------------- pipelined f32 GEMM core, packed-FMA microtile --------------
__device__ __forceinline__ void gemm_core(
    const float* __restrict__ A, const float* __restrict__ B, float* __restrict__ C,
    int K, int lda, int ldb, int ldc, int row0, int col0)
{
  __shared__ __align__(16) float As[2][16][68];
  __shared__ __align__(16) float Bs[2][16][68];
  const int tid = threadIdx.x;
  const int tx = tid & 15, ty = tid >> 4;
  const int ar = tid >> 2;
  const int ak = (tid & 3) * 4;
  const int bk = tid >> 4;
  const int bc = (tid & 15) * 4;

  const int nk = K >> 4;
  float4 a4 = *reinterpret_cast<const float4*>(&A[(row0 + ar) * lda + ak]);
  float4 b4 = *reinterpret_cast<const float4*>(&B[bk * ldb + col0 + bc]);
  {
    As[0][ak + 0][ar] = a4.x; As[0][ak + 1][ar] = a4.y;
    As[0][ak + 2][ar] = a4.z; As[0][ak + 3][ar] = a4.w;
    *reinterpret_cast<float4*>(&Bs[0][bk][bc]) = b4;
  }

  v2f acc01[4] = {};
  v2f acc23[4] = {};
  for (int t = 0; t < nk; ++t) {
    const int cur = t & 1;
    if (t + 1 < nk) {
      int k0 = (t + 1) * 16;
      a4 = *reinterpret_cast<const float4*>(&A[(row0 + ar) * lda + k0 + ak]);
      b4 = *reinterpret_cast<const float4*>(&B[(k0 + bk) * ldb + col0 + bc]);
    }
    __syncthreads();
#pragma unroll
    for (int kk = 0; kk < 16; ++kk) {
      float4 av = *reinterpret_cast<const float4*>(&As[cur][kk][ty * 4]);
      float4 bv = *reinterpret_cast<const float4*>(&Bs[cur][kk][tx * 4]);
      v2f b01; b01.x = bv.x; b01.y = bv.y;
      v2f b23; b23.x = bv.z; b23.y = bv.w;
      float a[4] = {av.x, av.y, av.z, av.w};
#pragma unroll
      for (int i = 0; i < 4; ++i) {
        v2f as; as.x = a[i]; as.y = a[i];
        acc01[i] += as * b01;
        acc23[i] += as * b23;
      }
    }
    if (t + 1 < nk) {
      const int nxt = cur ^ 1;
      As[nxt][ak + 0][ar] = a4.x; As[nxt][ak + 1][ar] = a4.y;
      As[nxt][ak + 2][ar] = a4.z; As[nxt][ak + 3][ar] = a4.w;
      *reinterpret_cast<float4*>(&Bs[nxt][bk][bc]) = b4;
    }
  }
#pragma unroll
  for (int i = 0; i < 4; ++i) {
    float4 o = make_float4(acc01[i].x, acc01[i].y, acc23[i].x, acc23[i].y);
    *reinterpret_cast<float4*>(&C[(row0 + ty * 4 + i) * ldc + col0 + tx * 4]) = o;
  }
}

__global__ __launch_bounds__(256) void gemm_tile(
    const float* __restrict__ A, const float* __restrict__ B, float* __restrict__ C,
    int M, int N, int K, int lda, int ldb, int ldc)
{
  gemm_core(A, B, C, K, lda, ldb, ldc, blockIdx.y * 64, blockIdx.x * 64);
}

// Fused k/v projections: one dispatch, blockIdx.x selects (B,C) pair.
__global__ __launch_bounds__(256) void gemm_kv(
    const float* __restrict__ A, const float* __restrict__ B0, const float* __restrict__ B1,
    float* __restrict__ C0, float* __restrict__ C1, int K, int lda, int ldb, int ldc)
{
  const float* B = blockIdx.x ? B1 : B0;
  float* C = blockIdx.x ? C1 : C0;
  gemm_core(A, B, C, K, lda, ldb, ldc, blockIdx.y * 64, 0);
}

// Fused pair of GEMMs over x-split grid: blockIdx.x < nx -> (A0,B0,C0).
__global__ __launch_bounds__(256) void gemm_dual(
    const float* __restrict__ A0, const float* __restrict__ A1,
    const float* __restrict__ B0, const float* __restrict__ B1,
    float* __restrict__ C0, float* __restrict__ C1,
    int K, int lda, int ldb, int ldc, int nx)
{
  const bool second = (int)blockIdx.x >= nx;
  const float* A = second ? A1 : A0;
  const float* B = second ? B1 : B0;
  float* C = second ? C1 : C0;
  const int bx = second ? (blockIdx.x - nx) : blockIdx.x;
  gemm_core(A, B, C, K, lda, ldb, ldc, blockIdx.y * 64, bx * 64);
}

// ---------------- RoPE cos/sin table (double trig once, f32 store) ----------
__global__ __launch_bounds__(256) void rope_table_kernel(float* __restrict__ ct,
                                                         float* __restrict__ st) {
  int tid = blockIdx.x * 256 + threadIdx.x;
  if (tid >= 2048 * 16) return;
  int pos = tid >> 4, i = tid & 15;
  double ang = (double)pos * pow(10000.0, -(double)i / 16.0);
  ct[tid] = (float)cos(ang);
  st[tid] = (float)sin(ang);
}

// ---------------- RoPE (first 32 dims) + RMSNorm ----------------------------
__global__ __launch_bounds__(256) void rope_rms_kernel(
    float* __restrict__ x, const float* __restrict__ g, int rows, int posShift,
    float* __restrict__ kS, const float* __restrict__ ct, const float* __restrict__ st)
{
  const int lane = threadIdx.x & 63;
  const int wid = threadIdx.x >> 6;
  const int r = blockIdx.x * 4 + wid;
  if (r >= rows) return;
  const int pos = r >> posShift;
  float val = x[r * 64 + lane];
  float p = __shfl_xor(val, 16, 64);
  float out = val;
  if (lane < 32) {
    int i = lane & 15;
    float cc = ct[pos * 16 + i], ss = st[pos * 16 + i];
    out = (lane < 16) ? (val * cc - p * ss) : (p * ss + val * cc);
  }
  float ms = wave_sum(out * out) * (1.0f / 64.0f);
  float rn = rsqrtf(ms + 1e-6f);
  float res = out * rn * ldv(g, lane);
  x[r * 64 + lane] = res;
  if (kS) {
    int f4 = (r >> 5) * 512 + (lane >> 2) * 32 + (r & 31);
    kS[f4 * 4 + (lane & 3)] = res;
  }
}

// ---------------- block-mean compression: kcT4 (d4-major) + vc --------------
__global__ void compress_kernel(const float* __restrict__ k, const float* __restrict__ v,
                                float* __restrict__ kcT4, float* __restrict__ vc)
{
  const int n = blockIdx.x;
  const int d = threadIdx.x;
  float sk = 0.f, sv = 0.f;
  for (int j = 0; j < 32; ++j) {
    sk += k[(n * 32 + j) * 64 + d];
    sv += v[(n * 32 + j) * 64 + d];
  }
  kcT4[(d >> 2) * 256 + n * 4 + (d & 3)] = sk * (1.0f / 32.0f);
  vc[n * 64 + d] = sv * (1.0f / 32.0f);
}

// ---------------- attention: one wave per (qpos, head) -----------------------
// Packed PV: e stored to per-wave LDS row; each lane owns a dim PAIR and one
// token half; per j: ds_read_b32(imm) + global_load_dwordx2(imm) + v_pk_fma.
// Halves merged once at the end via shfl_xor(,32). QK packed (pk_fma).
// sc/top-k path untouched (bitwise) so selection cannot flip.
__global__ __launch_bounds__(256) void attn_kernel(
    const float* __restrict__ q, const float* __restrict__ kS, const float* __restrict__ vbuf,
    const float* __restrict__ kcT4, const float* __restrict__ vc,
    const float* __restrict__ w_gate, const float* __restrict__ b_gate,
    const float* __restrict__ sink, float* __restrict__ mixed)
{
  __shared__ __align__(16) float shq[4][64];
  __shared__ float shp[4][64];
  __shared__ int shsel[4][16];
  const int lane = threadIdx.x & 63;
  const int wid = threadIdx.x >> 6;
  const int bid = 4095 - blockIdx.x;    // LJF: heaviest (large qpos) first
  const int r = bid * 4 + wid;          // r = qpos*8 + h
  const int qpos = r >> 3, h = r & 7;
  const float scale = 0.125f;

  float qv = q[r * 64 + lane];
  shq[wid][lane] = qv;

  // ---- gate ----
  float z0 = qv * ldv(w_gate, lane * 3 + 0);
  float z1 = qv * ldv(w_gate, lane * 3 + 1);
  float z2 = qv * ldv(w_gate, lane * 3 + 2);
  z0 = wave_sum(z0) + ldv(b_gate, 0);
  z1 = wave_sum(z1) + ldv(b_gate, 1);
  z2 = wave_sum(z2) + ldv(b_gate, 2);
  float ga0 = 1.f / (1.f + expf(-z0));
  float ga1 = 1.f / (1.f + expf(-z1));
  float ga2 = 1.f / (1.f + expf(-z2));
  float gs = fmaxf(ga0 + ga1 + ga2, 1e-6f);
  float ginv = 1.f / gs;
  ga0 *= ginv; ga1 *= ginv; ga2 *= ginv;

  const float4* qr = reinterpret_cast<const float4*>(&shq[wid][0]);
  const float4* ks4 = reinterpret_cast<const float4*>(kS);
  const float4* kct = reinterpret_cast<const float4*>(kcT4);  // [16][64]
  const float snk = ldv(sink, h);
  const int nv = (qpos + 1) >> 5;

  // per-lane PV constants
  const float* pp = &shp[wid][lane & 32];  // my half's p base (LDS)
  const int dimoff = (lane & 31) << 1;     // dim pair 2*(lane&31)

  // Packed PV over one 64-token chunk: halves at v0 (tokens 0-31, p lanes
  // 0-31) and handled by lane<32 / lane>=32 respectively via caller's vp.
  auto pvchunk = [&](const float* vp) -> v2f {
    v2f c0 = {0.f, 0.f}, c1 = {0.f, 0.f}, c2 = {0.f, 0.f}, c3 = {0.f, 0.f};
#pragma unroll
    for (int j = 0; j < 16; j += 4) {
      float p0 = pp[j + 0], p1 = pp[j + 1], p2 = pp[j + 2], p3 = pp[j + 3];
      float2 w0 = *reinterpret_cast<const float2*>(vp + (j + 0) * 64);
      float2 w1 = *reinterpret_cast<const float2*>(vp + (j + 1) * 64);
      float2 w2 = *reinterpret_cast<const float2*>(vp + (j + 2) * 64);
      float2 w3 = *reinterpret_cast<const float2*>(vp + (j + 3) * 64);
      c0 += (v2f){p0, p0} * (v2f){w0.x, w0.y};
      c1 += (v2f){p1, p1} * (v2f){w1.x, w1.y};
      c2 += (v2f){p2, p2} * (v2f){w2.x, w2.y};
      c3 += (v2f){p3, p3} * (v2f){w3.x, w3.y};
    }
    const float* pq = pp + 16;
    const float* vq = vp + 1024;
#pragma unroll
    for (int j = 0; j < 16; j += 4) {
      float p0 = pq[j + 0], p1 = pq[j + 1], p2 = pq[j + 2], p3 = pq[j + 3];
      float2 w0 = *reinterpret_cast<const float2*>(vq + (j + 0) * 64);
      float2 w1 = *reinterpret_cast<const float2*>(vq + (j + 1) * 64);
      float2 w2 = *reinterpret_cast<const float2*>(vq + (j + 2) * 64);
      float2 w3 = *reinterpret_cast<const float2*>(vq + (j + 3) * 64);
      c0 += (v2f){p0, p0} * (v2f){w0.x, w0.y};
      c1 += (v2f){p1, p1} * (v2f){w1.x, w1.y};
      c2 += (v2f){p2, p2} * (v2f){w2.x, w2.y};
      c3 += (v2f){p3, p3} * (v2f){w3.x, w3.y};
    }
    return (c0 + c1) + (c2 + c3);
  };

  // ---- compressed scores (lane = block index) — UNCHANGED (top-k bitwise) ----
  float sc;
  {
    float d0 = 0.f, d1 = 0.f;
#pragma unroll 1
    for (int i = 0; i < 16; i += 2) {
      float4 q0 = qr[i],     k0 = kct[i * 64 + lane];
      float4 q1 = qr[i + 1], k1 = kct[(i + 1) * 64 + lane];
      d0 += q0.x * k0.x + q0.z * k0.z;
      d1 += q0.y * k0.y + q0.w * k0.w;
      d0 += q1.x * k1.x + q1.z * k1.z;
      d1 += q1.y * k1.y + q1.w * k1.w;
    }
    sc = (d0 + d1) * scale;
  }

  v2f comp2 = {0.f, 0.f};
  if (nv > 0) {
    float scomp = (lane < nv) ? sc : NEGBIG;
    float m = fmaxf(wave_max(scomp), snk);
    float e = (lane < nv) ? expf(sc - m) : 0.f;
    float S = wave_sum(e) + expf(snk - m);
    float pn = e / S;   // zero for lane >= nv
    shp[wid][lane] = pn;
    const float* vp = vc + ((lane & 32) << 6) + dimoff;   // half B starts at row 32
    comp2 = pvchunk(vp);
  }

  // ---- top-16 block selection (jax.lax.top_k tie semantics) ----
  {
    float selv = (lane < nv) ? sc : -FLT_MAX;
#pragma unroll
    for (int it = 0; it < 16; ++it) {
      float bv = selv; int bi = lane;
#pragma unroll
      for (int off = 32; off; off >>= 1) {
        float ov = __shfl_xor(bv, off, 64);
        int oi = __shfl_xor(bi, off, 64);
        if (ov > bv || (ov == bv && oi < bi)) { bv = ov; bi = oi; }
      }
      if (lane == 0) shsel[wid][it] = bi;
      if (lane == bi) selv = -INFINITY;
    }
  }

  // ---- selected branch: 8 chunks x 2 blocks ----
  float M = NEGBIG, S = 0.f;
  v2f osel2 = {0.f, 0.f};
#pragma unroll 1
  for (int c = 0; c < 8; ++c) {
    int b0 = shsel[wid][2 * c], b1 = shsel[wid][2 * c + 1];
    int base0 = b0 * 32, base1 = b1 * 32;
    if (base0 > qpos && base1 > qpos) continue;
    int myb = (lane < 32) ? b0 : b1;
    int tok = myb * 32 + (lane & 31);
    bool ok = (tok <= qpos);
    const float4* kp = ks4 + myb * 512 + (lane & 31);
    float s = ok ? qk_dot(qr, kp) * scale : NEGBIG;
    float Mn = fmaxf(M, wave_max(s));
    float e = ok ? expf(s - Mn) : 0.f;
    float cs = wave_sum(e);
    float corr = expf(M - Mn);
    S = S * corr + cs;
    shp[wid][lane] = e;
    const float* vp = vbuf + ((lane < 32) ? base0 : base1) * 64 + dimoff;
    v2f pa = pvchunk(vp);
    osel2 = osel2 * (v2f){corr, corr} + pa;
    M = Mn;
  }
  {
    float si = 1.f / S;
    osel2 *= (v2f){si, si};
  }

  // ---- sliding-window branch: aligned 32-token sub-blocks, 2 per iter ----
  float Mw = NEGBIG, Sw = 0.f;
  v2f osw2 = {0.f, 0.f};
  int kstart = qpos - 511; if (kstart < 0) kstart = 0;
  int sbf = kstart >> 5, sbl = qpos >> 5;
#pragma unroll 1
  for (int sb = sbf; sb <= sbl; sb += 2) {
    int sb1 = sb + 1;
    bool v1ok = (sb1 <= sbl);
    int sb1c = v1ok ? sb1 : sb;            // clamp for safe loads
    int myb = (lane < 32) ? sb : sb1c;
    int tok = myb * 32 + (lane & 31);
    bool ok = (tok >= kstart) && (tok <= qpos) && ((lane < 32) || v1ok);
    const float4* kp = ks4 + myb * 512 + (lane & 31);
    float s = ok ? qk_dot(qr, kp) * scale : NEGBIG;
    float Mn = fmaxf(Mw, wave_max(s));
    float e = ok ? expf(s - Mn) : 0.f;
    float cs = wave_sum(e);
    float corr = expf(Mw - Mn);
    Sw = Sw * corr + cs;
    shp[wid][lane] = e;
    const float* vp = vbuf + ((lane < 32) ? sb : sb1c) * 2048 + dimoff;
    v2f pa = pvchunk(vp);
    osw2 = osw2 * (v2f){corr, corr} + pa;
    Mw = Mn;
  }
  {
    float Mf = fmaxf(Mw, snk);
    float corr = expf(Mw - Mf);
    float Sf = Sw * corr + expf(snk - Mf);
    float sf = corr / Sf;
    osw2 *= (v2f){sf, sf};
  }

  v2f mix2 = (v2f){ga0, ga0} * comp2 + (v2f){ga1, ga1} * osel2 + (v2f){ga2, ga2} * osw2;
  mix2.x += __shfl_xor(mix2.x, 32, 64);
  mix2.y += __shfl_xor(mix2.y, 32, 64);
  if (lane < 32)
    *reinterpret_cast<float2*>(&mixed[r * 64 + dimoff]) = make_float2(mix2.x, mix2.y);
}

// ---------------- launch ----------------
extern "C" void kernel_launch(void* const* d_in, const int* in_sizes, int n_in,
                              void* d_out, int out_size, void* d_ws, size_t ws_size,
                              hipStream_t stream) {
  const float* h      = (const float*)d_in[0];
  const float* w_qc   = (const float*)d_in[1];
  const float* w_qup  = (const float*)d_in[2];
  const float* w_k    = (const float*)d_in[3];
  const float* w_v    = (const float*)d_in[4];
  const float* g_qn   = (const float*)d_in[5];
  const float* g_kn   = (const float*)d_in[6];
  const float* w_gate = (const float*)d_in[7];
  const float* b_gate = (const float*)d_in[8];
  const float* sink   = (const float*)d_in[9];
  const float* wog    = (const float*)d_in[10];
  const float* w_out  = (const float*)d_in[11];
  float* out = (float*)d_out;

  float* ws = (float*)d_ws;
  float* hc  = ws;                    // 2048*256
  float* qb  = hc + 2048 * 256;       // 2048*512
  float* kb  = qb + 2048 * 512;       // 2048*64
  float* vb  = kb + 2048 * 64;        // 2048*64
  float* vc  = vb + 2048 * 64;        // 64*64
  float* mx  = vc + 64 * 64;          // 2048*512
  float* y1  = mx + 2048 * 512;       // 2048*1024
  float* kS  = y1 + 2048 * 1024;      // 2048*64 block-local K
  float* kct4 = kS + 2048 * 64;       // 16*64*4
  float* ct  = kct4 + 16 * 64 * 4;    // 2048*16 rope cos
  float* st  = ct + 2048 * 16;        // 2048*16 rope sin

  dim3 blk(256);
  rope_table_kernel<<<dim3(128), blk, 0, stream>>>(ct, st);
  gemm_tile<<<dim3(4, 32), blk, 0, stream>>>(h, w_qc, hc, 2048, 256, 1024, 1024, 256, 256);
  gemm_tile<<<dim3(8, 32), blk, 0, stream>>>(hc, w_qup, qb, 2048, 512, 256, 256, 512, 512);
  gemm_kv<<<dim3(2, 32), blk, 0, stream>>>(h, w_k, w_v, kb, vb, 1024, 1024, 64, 64);
  rope_rms_kernel<<<dim3(4096), blk, 0, stream>>>(qb, g_qn, 16384, 3, nullptr, ct, st);
  rope_rms_kernel<<<dim3(512), blk, 0, stream>>>(kb, g_kn, 2048, 0, kS, ct, st);
  compress_kernel<<<dim3(64), dim3(64), 0, stream>>>(kb, vb, kct4, vc);
  attn_kernel<<<dim3(4096), blk, 0, stream>>>(qb, kS, vb, kct4, vc, w_gate, b_gate, sink, mx);
  gemm_dual<<<dim3(16, 32), blk, 0, stream>>>(mx, mx + 256, wog, wog + 256 * 512,
                                              y1, y1 + 512, 256, 512, 512, 1024, 8);
  gemm_tile<<<dim3(16, 32), blk, 0, stream>>>(y1, w_out, out, 2048, 1024, 1024, 1024, 1024, 1024);
}

// Round 19
// 477.390 us; speedup vs baseline: 1.2041x; 1.2041x over previous
//
#include <hip/hip_runtime.h>
#include <hip/hip_bf16.h>
#include <float.h>
#include <math.h>

typedef __hip_bfloat16 bf16;
typedef float v2f __attribute__((ext_vector_type(2)));

#define NEGBIG (-1e30f)

__device__ __forceinline__ float ldv(const float* p, int i) { return p[i]; }

__device__ __forceinline__ float wave_sum(float v) {
#pragma unroll
  for (int off = 32; off; off >>= 1) v += __shfl_xor(v, off, 64);
  return v;
}
__device__ __forceinline__ float wave_max(float v) {
#pragma unroll
  for (int off = 32; off; off >>= 1) v = fmaxf(v, __shfl_xor(v, off, 64));
  return v;
}

__device__ __forceinline__ float rdlane(float v, int l) {
  return __uint_as_float(__builtin_amdgcn_readlane(__float_as_uint(v), l));
}

// PV over 16 tokens: p = lanes L0..L0+15 of e (readlane, literal -> SALU
// broadcast, no LDS), V rows at vp + t*64 floats (imm offsets). 4 chains.
template <int L0>
__device__ __forceinline__ void pv16(const float* __restrict__ vp, float e,
                                     float& a0, float& a1, float& a2, float& a3) {
#pragma unroll
  for (int t = 0; t < 16; t += 4) {
    float p0 = rdlane(e, L0 + t + 0);
    float p1 = rdlane(e, L0 + t + 1);
    float p2 = rdlane(e, L0 + t + 2);
    float p3 = rdlane(e, L0 + t + 3);
    a0 += p0 * vp[(t + 0) * 64];
    a1 += p1 * vp[(t + 1) * 64];
    a2 += p2 * vp[(t + 2) * 64];
    a3 += p3 * vp[(t + 3) * 64];
  }
}

// QK dot against one 32-token K block slice, packed (v_pk_fma_f32) — r18's
// validated numerics (absmax unchanged). 16 pk-FMA per token-dot.
__device__ __forceinline__ float qk_dot(const float4* __restrict__ qr,
                                        const float4* __restrict__ kp) {
  v2f d01 = {0.f, 0.f}, d23 = {0.f, 0.f};
#pragma unroll 1
  for (int i = 0; i < 16; i += 2) {
    float4 q0 = qr[i],     k0 = kp[i * 32];
    float4 q1 = qr[i + 1], k1 = kp[i * 32 + 32];
    d01 += (v2f){q0.x, q0.y} * (v2f){k0.x, k0.y};
    d23 += (v2f){q0.z, q0.w} * (v2f){k0.z, k0.w};
    d01 += (v2f){q1.x, q1.y} * (v2f){k1.x, k1.y};
    d23 += (v2f){q1.z, q1.w} * (v2f){k1.z, k1.w};
  }
  v2f d = d01 + d23;
  return d.x + d.y;
}

// ---------------- pipelined f32 GEMM core, packed-FMA microtile --------------
__device__ __forceinline__ void gemm_core(
    const float* __restrict__ A, const float* __restrict__ B, float* __restrict__ C,
    int K, int lda, int ldb, int ldc, int row0, int col0)
{
  __shared__ __align__(16) float As[2][16][68];
  __shared__ __align__(16) float Bs[2][16][68];
  const int tid = threadIdx.x;
  const int tx = tid & 15, ty = tid >> 4;
  const int ar = tid >> 2;
  const int ak = (tid & 3) * 4;
  const int bk = tid >> 4;
  const int bc = (tid & 15) * 4;

  const int nk = K >> 4;
  float4 a4 = *reinterpret_cast<const float4*>(&A[(row0 + ar) * lda + ak]);
  float4 b4 = *reinterpret_cast<const float4*>(&B[bk * ldb + col0 + bc]);
  {
    As[0][ak + 0][ar] = a4.x; As[0][ak + 1][ar] = a4.y;
    As[0][ak + 2][ar] = a4.z; As[0][ak + 3][ar] = a4.w;
    *reinterpret_cast<float4*>(&Bs[0][bk][bc]) = b4;
  }

  v2f acc01[4] = {};
  v2f acc23[4] = {};
  for (int t = 0; t < nk; ++t) {
    const int cur = t & 1;
    if (t + 1 < nk) {
      int k0 = (t + 1) * 16;
      a4 = *reinterpret_cast<const float4*>(&A[(row0 + ar) * lda + k0 + ak]);
      b4 = *reinterpret_cast<const float4*>(&B[(k0 + bk) * ldb + col0 + bc]);
    }
    __syncthreads();
#pragma unroll
    for (int kk = 0; kk < 16; ++kk) {
      float4 av = *reinterpret_cast<const float4*>(&As[cur][kk][ty * 4]);
      float4 bv = *reinterpret_cast<const float4*>(&Bs[cur][kk][tx * 4]);
      v2f b01; b01.x = bv.x; b01.y = bv.y;
      v2f b23; b23.x = bv.z; b23.y = bv.w;
      float a[4] = {av.x, av.y, av.z, av.w};
#pragma unroll
      for (int i = 0; i < 4; ++i) {
        v2f as; as.x = a[i]; as.y = a[i];
        acc01[i] += as * b01;
        acc23[i] += as * b23;
      }
    }
    if (t + 1 < nk) {
      const int nxt = cur ^ 1;
      As[nxt][ak + 0][ar] = a4.x; As[nxt][ak + 1][ar] = a4.y;
      As[nxt][ak + 2][ar] = a4.z; As[nxt][ak + 3][ar] = a4.w;
      *reinterpret_cast<float4*>(&Bs[nxt][bk][bc]) = b4;
    }
  }
#pragma unroll
  for (int i = 0; i < 4; ++i) {
    float4 o = make_float4(acc01[i].x, acc01[i].y, acc23[i].x, acc23[i].y);
    *reinterpret_cast<float4*>(&C[(row0 + ty * 4 + i) * ldc + col0 + tx * 4]) = o;
  }
}

__global__ __launch_bounds__(256) void gemm_tile(
    const float* __restrict__ A, const float* __restrict__ B, float* __restrict__ C,
    int M, int N, int K, int lda, int ldb, int ldc)
{
  gemm_core(A, B, C, K, lda, ldb, ldc, blockIdx.y * 64, blockIdx.x * 64);
}

// Fused k/v projections: one dispatch, blockIdx.x selects (B,C) pair.
__global__ __launch_bounds__(256) void gemm_kv(
    const float* __restrict__ A, const float* __restrict__ B0, const float* __restrict__ B1,
    float* __restrict__ C0, float* __restrict__ C1, int K, int lda, int ldb, int ldc)
{
  const float* B = blockIdx.x ? B1 : B0;
  float* C = blockIdx.x ? C1 : C0;
  gemm_core(A, B, C, K, lda, ldb, ldc, blockIdx.y * 64, 0);
}

// Fused pair of GEMMs over x-split grid: blockIdx.x < nx -> (A0,B0,C0).
__global__ __launch_bounds__(256) void gemm_dual(
    const float* __restrict__ A0, const float* __restrict__ A1,
    const float* __restrict__ B0, const float* __restrict__ B1,
    float* __restrict__ C0, float* __restrict__ C1,
    int K, int lda, int ldb, int ldc, int nx)
{
  const bool second = (int)blockIdx.x >= nx;
  const float* A = second ? A1 : A0;
  const float* B = second ? B1 : B0;
  float* C = second ? C1 : C0;
  const int bx = second ? (blockIdx.x - nx) : blockIdx.x;
  gemm_core(A, B, C, K, lda, ldb, ldc, blockIdx.y * 64, bx * 64);
}

// ---------------- RoPE cos/sin table (double trig once, f32 store) ----------
__global__ __launch_bounds__(256) void rope_table_kernel(float* __restrict__ ct,
                                                         float* __restrict__ st) {
  int tid = blockIdx.x * 256 + threadIdx.x;
  if (tid >= 2048 * 16) return;
  int pos = tid >> 4, i = tid & 15;
  double ang = (double)pos * pow(10000.0, -(double)i / 16.0);
  ct[tid] = (float)cos(ang);
  st[tid] = (float)sin(ang);
}

// ---------------- RoPE (first 32 dims) + RMSNorm ----------------------------
__global__ __launch_bounds__(256) void rope_rms_kernel(
    float* __restrict__ x, const float* __restrict__ g, int rows, int posShift,
    float* __restrict__ kS, const float* __restrict__ ct, const float* __restrict__ st)
{
  const int lane = threadIdx.x & 63;
  const int wid = threadIdx.x >> 6;
  const int r = blockIdx.x * 4 + wid;
  if (r >= rows) return;
  const int pos = r >> posShift;
  float val = x[r * 64 + lane];
  float p = __shfl_xor(val, 16, 64);
  float out = val;
  if (lane < 32) {
    int i = lane & 15;
    float cc = ct[pos * 16 + i], ss = st[pos * 16 + i];
    out = (lane < 16) ? (val * cc - p * ss) : (p * ss + val * cc);
  }
  float ms = wave_sum(out * out) * (1.0f / 64.0f);
  float rn = rsqrtf(ms + 1e-6f);
  float res = out * rn * ldv(g, lane);
  x[r * 64 + lane] = res;
  if (kS) {
    int f4 = (r >> 5) * 512 + (lane >> 2) * 32 + (r & 31);
    kS[f4 * 4 + (lane & 3)] = res;
  }
}

// ---------------- block-mean compression: kcT4 (d4-major) + vc --------------
__global__ void compress_kernel(const float* __restrict__ k, const float* __restrict__ v,
                                float* __restrict__ kcT4, float* __restrict__ vc)
{
  const int n = blockIdx.x;
  const int d = threadIdx.x;
  float sk = 0.f, sv = 0.f;
  for (int j = 0; j < 32; ++j) {
    sk += k[(n * 32 + j) * 64 + d];
    sv += v[(n * 32 + j) * 64 + d];
  }
  kcT4[(d >> 2) * 256 + n * 4 + (d & 3)] = sk * (1.0f / 32.0f);
  vc[n * 64 + d] = sv * (1.0f / 32.0f);
}

// ---------------- attention: one wave per (qpos, head) -----------------------
// r16 structure (readlane PV — p stays in registers, no LDS round-trip) with
// r18's packed qk_dot (fewer QK issue slots). LJF block order.
__global__ __launch_bounds__(256) void attn_kernel(
    const float* __restrict__ q, const float* __restrict__ kS, const float* __restrict__ vbuf,
    const float* __restrict__ kcT4, const float* __restrict__ vc,
    const float* __restrict__ w_gate, const float* __restrict__ b_gate,
    const float* __restrict__ sink, float* __restrict__ mixed)
{
  __shared__ __align__(16) float shq[4][64];
  __shared__ int shsel[4][16];
  const int lane = threadIdx.x & 63;
  const int wid = threadIdx.x >> 6;
  const int bid = 4095 - blockIdx.x;    // LJF: heaviest (large qpos) first
  const int r = bid * 4 + wid;          // r = qpos*8 + h
  const int qpos = r >> 3, h = r & 7;
  const float scale = 0.125f;

  float qv = q[r * 64 + lane];
  shq[wid][lane] = qv;

  // ---- gate ----
  float z0 = qv * ldv(w_gate, lane * 3 + 0);
  float z1 = qv * ldv(w_gate, lane * 3 + 1);
  float z2 = qv * ldv(w_gate, lane * 3 + 2);
  z0 = wave_sum(z0) + ldv(b_gate, 0);
  z1 = wave_sum(z1) + ldv(b_gate, 1);
  z2 = wave_sum(z2) + ldv(b_gate, 2);
  float ga0 = 1.f / (1.f + expf(-z0));
  float ga1 = 1.f / (1.f + expf(-z1));
  float ga2 = 1.f / (1.f + expf(-z2));
  float gs = fmaxf(ga0 + ga1 + ga2, 1e-6f);
  float ginv = 1.f / gs;
  ga0 *= ginv; ga1 *= ginv; ga2 *= ginv;

  const float4* qr = reinterpret_cast<const float4*>(&shq[wid][0]);
  const float4* ks4 = reinterpret_cast<const float4*>(kS);
  const float4* kct = reinterpret_cast<const float4*>(kcT4);  // [16][64]
  const float snk = ldv(sink, h);
  const int nv = (qpos + 1) >> 5;

  // ---- compressed scores (lane = block index) — scalar chains (top-k bitwise) ----
  float sc;
  {
    float d0 = 0.f, d1 = 0.f;
#pragma unroll 1
    for (int i = 0; i < 16; i += 2) {
      float4 q0 = qr[i],     k0 = kct[i * 64 + lane];
      float4 q1 = qr[i + 1], k1 = kct[(i + 1) * 64 + lane];
      d0 += q0.x * k0.x + q0.z * k0.z;
      d1 += q0.y * k0.y + q0.w * k0.w;
      d0 += q1.x * k1.x + q1.z * k1.z;
      d1 += q1.y * k1.y + q1.w * k1.w;
    }
    sc = (d0 + d1) * scale;
  }

  float comp_out = 0.f;
  if (nv > 0) {
    float scomp = (lane < nv) ? sc : NEGBIG;
    float m = fmaxf(wave_max(scomp), snk);
    float e = (lane < nv) ? expf(sc - m) : 0.f;
    float S = wave_sum(e) + expf(snk - m);
    float pn = e / S;   // zero for lane >= nv
    const float* vcp = vc + lane;
    float c0 = 0.f, c1 = 0.f, c2 = 0.f, c3 = 0.f;
    pv16<0>(vcp, pn, c0, c1, c2, c3);
    pv16<16>(vcp + 1024, pn, c0, c1, c2, c3);
    pv16<32>(vcp + 2048, pn, c0, c1, c2, c3);
    pv16<48>(vcp + 3072, pn, c0, c1, c2, c3);
    comp_out = (c0 + c1) + (c2 + c3);
  }

  // ---- top-16 block selection (jax.lax.top_k tie semantics) ----
  {
    float selv = (lane < nv) ? sc : -FLT_MAX;
#pragma unroll
    for (int it = 0; it < 16; ++it) {
      float bv = selv; int bi = lane;
#pragma unroll
      for (int off = 32; off; off >>= 1) {
        float ov = __shfl_xor(bv, off, 64);
        int oi = __shfl_xor(bi, off, 64);
        if (ov > bv || (ov == bv && oi < bi)) { bv = ov; bi = oi; }
      }
      if (lane == 0) shsel[wid][it] = bi;
      if (lane == bi) selv = -INFINITY;
    }
  }

  // ---- selected branch: 8 chunks x 2 blocks ----
  float M = NEGBIG, S = 0.f, osel = 0.f;
#pragma unroll 1
  for (int c = 0; c < 8; ++c) {
    int b0 = shsel[wid][2 * c], b1 = shsel[wid][2 * c + 1];
    int base0 = b0 * 32, base1 = b1 * 32;
    if (base0 > qpos && base1 > qpos) continue;
    int myb = (lane < 32) ? b0 : b1;
    int tok = myb * 32 + (lane & 31);
    bool ok = (tok <= qpos);
    const float4* kp = ks4 + myb * 512 + (lane & 31);
    float s = ok ? qk_dot(qr, kp) * scale : NEGBIG;
    float Mn = fmaxf(M, wave_max(s));
    float e = ok ? expf(s - Mn) : 0.f;
    float cs = wave_sum(e);
    float corr = expf(M - Mn);
    S = S * corr + cs;
    const float* v0 = vbuf + base0 * 64 + lane;
    const float* v1 = vbuf + base1 * 64 + lane;
    float a0 = 0.f, a1 = 0.f, a2 = 0.f, a3 = 0.f;
    pv16<0>(v0, e, a0, a1, a2, a3);
    pv16<16>(v0 + 1024, e, a0, a1, a2, a3);
    pv16<32>(v1, e, a0, a1, a2, a3);
    pv16<48>(v1 + 1024, e, a0, a1, a2, a3);
    osel = osel * corr + ((a0 + a1) + (a2 + a3));
    M = Mn;
  }
  osel /= S;

  // ---- sliding-window branch: aligned 32-token sub-blocks, 2 per iter ----
  float Mw = NEGBIG, Sw = 0.f, osw = 0.f;
  int kstart = qpos - 511; if (kstart < 0) kstart = 0;
  int sbf = kstart >> 5, sbl = qpos >> 5;
#pragma unroll 1
  for (int sb = sbf; sb <= sbl; sb += 2) {
    int sb1 = sb + 1;
    bool v1ok = (sb1 <= sbl);
    int sb1c = v1ok ? sb1 : sb;            // clamp for safe loads
    int myb = (lane < 32) ? sb : sb1c;
    int tok = myb * 32 + (lane & 31);
    bool ok = (tok >= kstart) && (tok <= qpos) && ((lane < 32) || v1ok);
    const float4* kp = ks4 + myb * 512 + (lane & 31);
    float s = ok ? qk_dot(qr, kp) * scale : NEGBIG;
    float Mn = fmaxf(Mw, wave_max(s));
    float e = ok ? expf(s - Mn) : 0.f;
    float cs = wave_sum(e);
    float corr = expf(Mw - Mn);
    Sw = Sw * corr + cs;
    const float* v0 = vbuf + sb * 2048 + lane;    // sb*32*64
    const float* v1 = vbuf + sb1c * 2048 + lane;
    float a0 = 0.f, a1 = 0.f, a2 = 0.f, a3 = 0.f;
    pv16<0>(v0, e, a0, a1, a2, a3);
    pv16<16>(v0 + 1024, e, a0, a1, a2, a3);
    pv16<32>(v1, e, a0, a1, a2, a3);
    pv16<48>(v1 + 1024, e, a0, a1, a2, a3);
    osw = osw * corr + ((a0 + a1) + (a2 + a3));
    Mw = Mn;
  }
  {
    float Mf = fmaxf(Mw, snk);
    float corr = expf(Mw - Mf);
    float Sf = Sw * corr + expf(snk - Mf);
    osw = osw * corr / Sf;
  }

  mixed[r * 64 + lane] = ga0 * comp_out + ga1 * osel + ga2 * osw;
}

// ---------------- launch ----------------
extern "C" void kernel_launch(void* const* d_in, const int* in_sizes, int n_in,
                              void* d_out, int out_size, void* d_ws, size_t ws_size,
                              hipStream_t stream) {
  const float* h      = (const float*)d_in[0];
  const float* w_qc   = (const float*)d_in[1];
  const float* w_qup  = (const float*)d_in[2];
  const float* w_k    = (const float*)d_in[3];
  const float* w_v    = (const float*)d_in[4];
  const float* g_qn   = (const float*)d_in[5];
  const float* g_kn   = (const float*)d_in[6];
  const float* w_gate = (const float*)d_in[7];
  const float* b_gate = (const float*)d_in[8];
  const float* sink   = (const float*)d_in[9];
  const float* wog    = (const float*)d_in[10];
  const float* w_out  = (const float*)d_in[11];
  float* out = (float*)d_out;

  float* ws = (float*)d_ws;
  float* hc  = ws;                    // 2048*256
  float* qb  = hc + 2048 * 256;       // 2048*512
  float* kb  = qb + 2048 * 512;       // 2048*64
  float* vb  = kb + 2048 * 64;        // 2048*64
  float* vc  = vb + 2048 * 64;        // 64*64
  float* mx  = vc + 64 * 64;          // 2048*512
  float* y1  = mx + 2048 * 512;       // 2048*1024
  float* kS  = y1 + 2048 * 1024;      // 2048*64 block-local K
  float* kct4 = kS + 2048 * 64;       // 16*64*4
  float* ct  = kct4 + 16 * 64 * 4;    // 2048*16 rope cos
  float* st  = ct + 2048 * 16;        // 2048*16 rope sin

  dim3 blk(256);
  rope_table_kernel<<<dim3(128), blk, 0, stream>>>(ct, st);
  gemm_tile<<<dim3(4, 32), blk, 0, stream>>>(h, w_qc, hc, 2048, 256, 1024, 1024, 256, 256);
  gemm_tile<<<dim3(8, 32), blk, 0, stream>>>(hc, w_qup, qb, 2048, 512, 256, 256, 512, 512);
  gemm_kv<<<dim3(2, 32), blk, 0, stream>>>(h, w_k, w_v, kb, vb, 1024, 1024, 64, 64);
  rope_rms_kernel<<<dim3(4096), blk, 0, stream>>>(qb, g_qn, 16384, 3, nullptr, ct, st);
  rope_rms_kernel<<<dim3(512), blk, 0, stream>>>(kb, g_kn, 2048, 0, kS, ct, st);
  compress_kernel<<<dim3(64), dim3(64), 0, stream>>>(kb, vb, kct4, vc);
  attn_kernel<<<dim3(4096), blk, 0, stream>>>(qb, kS, vb, kct4, vc, w_gate, b_gate, sink, mx);
  gemm_dual<<<dim3(16, 32), blk, 0, stream>>>(mx, mx + 256, wog, wog + 256 * 512,
                                              y1, y1 + 512, 256, 512, 512, 1024, 8);
  gemm_tile<<<dim3(16, 32), blk, 0, stream>>>(y1, w_out, out, 2048, 1024, 1024, 1024, 1024, 1024);
}